// Round 12
// baseline (555.903 us; speedup 1.0000x reference)
//
#include <hip/hip_runtime.h>
#include <hip/hip_bf16.h>

#define B_ 16
#define S_ 4096
#define DM_ 1280
#define DC_ 768
#define NC_ 384
#define SCALE_ 0.07905694150420949f

typedef __attribute__((ext_vector_type(8))) short bf16x8;
typedef __attribute__((ext_vector_type(4))) float f32x4;
typedef __attribute__((ext_vector_type(4))) unsigned short u16x4;

#define S_BARRIER() asm volatile("s_barrier" ::: "memory")
#define WAIT_VM(n) asm volatile("s_waitcnt vmcnt(" #n ")" ::: "memory")
#define WAIT_LGKM0() asm volatile("s_waitcnt lgkmcnt(0)" ::: "memory")

__device__ __forceinline__ unsigned short f2bf(float f) {
    unsigned int u = __builtin_bit_cast(unsigned int, f);
    u = (u + 0x7FFFu + ((u >> 16) & 1u)) >> 16;
    return (unsigned short)u;
}

__device__ __forceinline__ bf16x8 pack8(float4 x0, float4 x1) {
    bf16x8 a;
    a[0] = __builtin_bit_cast(short, __float2bfloat16(x0.x));
    a[1] = __builtin_bit_cast(short, __float2bfloat16(x0.y));
    a[2] = __builtin_bit_cast(short, __float2bfloat16(x0.z));
    a[3] = __builtin_bit_cast(short, __float2bfloat16(x0.w));
    a[4] = __builtin_bit_cast(short, __float2bfloat16(x1.x));
    a[5] = __builtin_bit_cast(short, __float2bfloat16(x1.y));
    a[6] = __builtin_bit_cast(short, __float2bfloat16(x1.z));
    a[7] = __builtin_bit_cast(short, __float2bfloat16(x1.w));
    return a;
}

__device__ __forceinline__ void gload16(const void* g, void* l) {
    __builtin_amdgcn_global_load_lds(
        (const __attribute__((address_space(1))) void*)g,
        (__attribute__((address_space(3))) void*)l, 16, 0, 0);
}

// ---------- merged prep: wq cvt + 5 transpose/cvt ----------
__device__ __forceinline__ void tcvt_body(const float* __restrict__ in,
                                          unsigned short* __restrict__ out,
                                          int R, int C, int bx, int by, int tid) {
    __shared__ float tile[32][33];
    int c0 = bx * 32, r0 = by * 32;
    int tx = tid & 31, ty = tid >> 5;
    for (int i = ty; i < 32; i += 8)
        tile[i][tx] = in[(size_t)(r0 + i) * C + c0 + tx];
    __syncthreads();
    for (int i = ty; i < 32; i += 8)
        out[(size_t)(c0 + i) * R + r0 + tx] = f2bf(tile[tx][i]);
}

__global__ __launch_bounds__(256)
void k_prep(const float* __restrict__ wq, const float* __restrict__ wk,
            const float* __restrict__ wv, const float* __restrict__ wkd,
            const float* __restrict__ wvd, const float* __restrict__ wout,
            unsigned short* __restrict__ wq_bf, unsigned short* __restrict__ wTk,
            unsigned short* __restrict__ wTv, unsigned short* __restrict__ wTkd,
            unsigned short* __restrict__ wTvd, unsigned short* __restrict__ woutT) {
    int bid = blockIdx.x, tid = threadIdx.x;
    if (bid < 1600) {
        int i = bid * 256 + tid;
        float4 v = ((const float4*)wq)[i];
        u16x4 o = { f2bf(v.x), f2bf(v.y), f2bf(v.z), f2bf(v.w) };
        ((u16x4*)wq_bf)[i] = o;
    } else if (bid < 2560) {
        int r = bid - 1600; tcvt_body(wk,  wTk,  DC_, DM_, r % 40, r / 40, tid);
    } else if (bid < 3520) {
        int r = bid - 2560; tcvt_body(wv,  wTv,  DC_, DM_, r % 40, r / 40, tid);
    } else if (bid < 4480) {
        int r = bid - 3520; tcvt_body(wkd, wTkd, DC_, DM_, r % 40, r / 40, tid);
    } else if (bid < 5440) {
        int r = bid - 4480; tcvt_body(wvd, wTvd, DC_, DM_, r % 40, r / 40, tid);
    } else {
        int r = bid - 5440; tcvt_body(wout, woutT, DM_, DM_, r % 40, r / 40, tid);
    }
}

// ---------- K/V projections via MFMA ----------
__global__ __launch_bounds__(256)
void k_projM(const float* __restrict__ enc,
             const unsigned short* __restrict__ wTk, const unsigned short* __restrict__ wTv,
             const unsigned short* __restrict__ wTkd, const unsigned short* __restrict__ wTvd,
             unsigned short* __restrict__ KV) {
    int bid = blockIdx.x;
    int j = bid / 80, rem = bid % 80, b = rem / 5, nt = rem % 5;
    int tid = threadIdx.x, w = tid >> 6, l = tid & 63, l15 = l & 15, l4 = l >> 4;
    int tok0 = (j < 2) ? 16 : ((j < 4) ? 0 : 32);
    const unsigned short* wT = (j == 0) ? wTk : (j == 1) ? wTv : (j == 2 || j == 4) ? wTkd : wTvd;
    const float* ap = enc + ((size_t)(b * 48 + tok0 + l15)) * DC_;
    f32x4 zero = {0.f, 0.f, 0.f, 0.f};
    f32x4 acc[4];
    #pragma unroll
    for (int t = 0; t < 4; t++) acc[t] = zero;
    for (int kk = 0; kk < 24; kk++) {
        const float4* hp = (const float4*)(ap + kk * 32 + l4 * 8);
        bf16x8 af = pack8(hp[0], hp[1]);
        #pragma unroll
        for (int t = 0; t < 4; t++) {
            int n0 = nt * 256 + w * 64 + t * 16;
            bf16x8 bf = *(const bf16x8*)(wT + (size_t)(n0 + l15) * DC_ + kk * 32 + l4 * 8);
            acc[t] = __builtin_amdgcn_mfma_f32_16x16x32_bf16(af, bf, acc[t], 0, 0, 0);
        }
    }
    #pragma unroll
    for (int t = 0; t < 4; t++) {
        int e = nt * 256 + w * 64 + t * 16 + l15;
        #pragma unroll
        for (int r = 0; r < 4; r++)
            KV[((size_t)(j * 16 + b) * 16 + l4 * 4 + r) * DM_ + e] = f2bf(acc[t][r]);
    }
}

// ---------- merged A/U build; outputs kk-major layouts ----------
// At2[b][40][384c][32d], Ut2[b][12][1280e][32c]
__global__ __launch_bounds__(256)
void k_au(const unsigned short* __restrict__ KV, const unsigned short* __restrict__ wqbf,
          const unsigned short* __restrict__ woutT,
          unsigned short* __restrict__ At2, unsigned short* __restrict__ Ut2) {
    int bid0 = blockIdx.x;
    bool isA = bid0 < 384;
    int bid = isA ? bid0 : bid0 - 384;
    int b = bid & 15, r_ = bid >> 4, x = r_ >> 3, h = r_ & 7;
    int tid = threadIdx.x, w = tid >> 6, l = tid & 63, l15 = l & 15, l4 = l >> 4;
    int xh = x * 8 + h;
    int jrow = isA ? (2 * x) : (2 * x + 1);
    const unsigned short* wmat = isA ? wqbf : woutT;
    float postscale = isA ? SCALE_ : ((x == 2) ? 1.0f : 0.5f);
    bf16x8 bfr[5];
    #pragma unroll
    for (int kk = 0; kk < 5; kk++)
        bfr[kk] = *(const bf16x8*)(KV + ((size_t)(jrow * 16 + b) * 16 + l15) * DM_ + h * 160 + kk * 32 + l4 * 8);
    f32x4 zero = {0.f, 0.f, 0.f, 0.f};
    for (int tt = 0; tt < 20; tt++) {
        int d0 = w * 320 + tt * 16;
        f32x4 acc = zero;
        if (isA) {
            #pragma unroll
            for (int kk = 0; kk < 5; kk++) {
                bf16x8 af = *(const bf16x8*)(wmat + (size_t)(d0 + l15) * DM_ + h * 160 + kk * 32 + l4 * 8);
                acc = __builtin_amdgcn_mfma_f32_16x16x32_bf16(af, bfr[kk], acc, 0, 0, 0);
            }
            int c = xh * 16 + l15;
            u16x4 pk;
            #pragma unroll
            for (int r = 0; r < 4; r++) pk[r] = f2bf(acc[r] * postscale);
            *(u16x4*)(At2 + ((size_t)(b * 40 + (d0 >> 5)) * NC_ + c) * 32 + (d0 & 31) + l4 * 4) = pk;
        } else {
            #pragma unroll
            for (int kk = 0; kk < 5; kk++) {
                bf16x8 af = *(const bf16x8*)(wmat + (size_t)(d0 + l15) * DM_ + h * 160 + kk * 32 + l4 * 8);
                acc = __builtin_amdgcn_mfma_f32_16x16x32_bf16(bfr[kk], af, acc, 0, 0, 0);
            }
            int e = d0 + l15;
            u16x4 pk;
            #pragma unroll
            for (int r = 0; r < 4; r++) pk[r] = f2bf(acc[r] * postscale);
            *(u16x4*)(Ut2 + ((size_t)(b * 12 + (xh >> 1)) * DM_ + e) * 32 + (xh & 1) * 16 + l4 * 4) = pk;
        }
    }
}

// ---------- scores: 128-s tile, single resident round, uniform 10-load pipeline ----------
__global__ __launch_bounds__(256, 2)
void k_scores8(const float* __restrict__ hid, const unsigned short* __restrict__ At2,
               unsigned short* __restrict__ P2) {
    __shared__ char smem[81920];                 // A 2x24KB @0; H 2x16KB @49152
    unsigned short* Apnl = (unsigned short*)smem;
    char* Hlds = smem + 49152;
    int bid = blockIdx.x;
    int orig = (bid & 7) * 64 + (bid >> 3);      // XCD-chunked: 2 batches per XCD
    int b = orig >> 5, st = orig & 31;
    int s0 = st * 128;
    int tid = threadIdx.x, w = tid >> 6, l = tid & 63, l15 = l & 15, l4 = l >> 4;
    int rdsw = (l4 ^ ((l15 >> 1) & 3)) * 8;
    const unsigned short* Ab = At2 + (size_t)b * 40 * NC_ * 32;
    const float* hsrc = hid + ((size_t)b * S_ + s0) * DM_;
    f32x4 zero = {0.f, 0.f, 0.f, 0.f};
    f32x4 acc[8][6];
    #pragma unroll
    for (int g = 0; g < 8; g++)
        #pragma unroll
        for (int cj = 0; cj < 6; cj++) acc[g][cj] = zero;

    auto stageA = [&](int kk, int ab) {          // 6 gload_lds
        const unsigned short* slab = Ab + (size_t)kk * (NC_ * 32);
        #pragma unroll
        for (int i = 0; i < 6; i++) {
            int idx = i * 256 + tid;
            int c = idx >> 2, m = (idx & 3) ^ ((c >> 1) & 3);
            gload16(slab + (size_t)c * 32 + m * 8, smem + ab * 24576 + idx * 16);
        }
    };
    auto stageH = [&](int kk, int hb) {          // 4 gload_lds (128 rows x 128B)
        #pragma unroll
        for (int i = 0; i < 4; i++) {
            int idx = i * 256 + tid;
            int r = idx >> 3, sg = (idx & 7) ^ (r & 7);
            gload16(hsrc + (size_t)r * DM_ + kk * 32 + sg * 4, Hlds + hb * 16384 + idx * 16);
        }
    };
    auto compute = [&](int ab, int hb) {
        #pragma unroll
        for (int sh = 0; sh < 2; sh++) {
            bf16x8 hpk[4];
            #pragma unroll
            for (int si = 0; si < 4; si++) {
                int r = sh * 64 + si * 16 + l15;
                float4 lo = *(const float4*)(Hlds + hb * 16384 + r * 128 + (((2 * l4) ^ (l15 & 7)) * 16));
                float4 hi = *(const float4*)(Hlds + hb * 16384 + r * 128 + (((2 * l4 + 1) ^ (l15 & 7)) * 16));
                hpk[si] = pack8(lo, hi);
            }
            __builtin_amdgcn_s_setprio(1);
            #pragma unroll
            for (int cj = 0; cj < 6; cj++) {
                bf16x8 af = *(const bf16x8*)&Apnl[ab * 12288 + (w * 96 + cj * 16 + l15) * 32 + rdsw];
                #pragma unroll
                for (int si = 0; si < 4; si++)
                    acc[sh * 4 + si][cj] = __builtin_amdgcn_mfma_f32_16x16x32_bf16(af, hpk[si], acc[sh * 4 + si][cj], 0, 0, 0);
            }
            __builtin_amdgcn_s_setprio(0);
        }
    };
    // uniform gload_lds stream; depth-1: issue tile kk+1 (10 loads), WAIT_VM(10) drains tile kk.
    auto SITER = [&](int kk) {
        stageA(kk + 1, (kk + 1) & 1);
        stageH(kk + 1, (kk + 1) & 1);
        WAIT_VM(10);
        S_BARRIER();
        compute(kk & 1, kk & 1);
        WAIT_LGKM0();
        S_BARRIER();
    };

    stageA(0, 0); stageH(0, 0);                  // queue = 10
    for (int k0 = 0; k0 < 38; k0 += 2) { SITER(k0); SITER(k0 + 1); }
    SITER(38);                                   // stages kk=39 -> buf 1
    WAIT_VM(0);
    S_BARRIER();
    compute(1, 1);

    // softmax per 16-c group; direct store to P2[b][kk2][s][32]
    unsigned short* P2b = P2 + (size_t)b * 12 * S_ * 32;
    #pragma unroll
    for (int g = 0; g < 8; g++) {
        int s_l = (g >> 2) * 64 + (g & 3) * 16 + l15;
        #pragma unroll
        for (int cj = 0; cj < 6; cj++) {
            float v0 = acc[g][cj][0], v1 = acc[g][cj][1], v2 = acc[g][cj][2], v3 = acc[g][cj][3];
            float mx = fmaxf(fmaxf(v0, v1), fmaxf(v2, v3));
            mx = fmaxf(mx, __shfl_xor(mx, 16));
            mx = fmaxf(mx, __shfl_xor(mx, 32));
            float e0 = __expf(v0 - mx), e1 = __expf(v1 - mx), e2 = __expf(v2 - mx), e3 = __expf(v3 - mx);
            float sm = e0 + e1 + e2 + e3;
            sm += __shfl_xor(sm, 16);
            sm += __shfl_xor(sm, 32);
            float rs = 1.0f / sm;
            u16x4 pk = { f2bf(e0 * rs), f2bf(e1 * rs), f2bf(e2 * rs), f2bf(e3 * rs) };
            int kk2 = w * 3 + (cj >> 1);
            int c32 = (cj & 1) * 16 + l4 * 4;
            *(u16x4*)(P2b + ((size_t)kk2 * S_ + s0 + s_l) * 32 + c32) = pk;
        }
    }
}

// ---------- PV: counted-vmcnt 3-buffer pipeline (uniform gload_lds stream) ----------
__global__ __launch_bounds__(256, 3)
void k_pv4(const unsigned short* __restrict__ P2, const unsigned short* __restrict__ Ut2,
           const float* __restrict__ hid, const float* __restrict__ bo,
           float* __restrict__ out) {
    __shared__ unsigned short Plds[3 * 4096];    // 3 x 8 KB
    __shared__ unsigned short Ulds[3 * 4096];
    int bid = blockIdx.x;
    int orig = (bid & 7) * 640 + (bid >> 3);     // XCD-chunked
    int b = orig / 320, rem = orig % 320;
    int st = rem / 10, ec = rem % 10;
    int s0 = st * 128, e0 = ec * 128;
    int tid = threadIdx.x, w = tid >> 6, l = tid & 63, l15 = l & 15, l4 = l >> 4;
    int wr = w >> 1, wc = w & 1;
    int rdsw = (l4 ^ ((l15 >> 1) & 3)) * 8;
    const unsigned short* Pb = P2 + (size_t)b * 12 * S_ * 32;
    const unsigned short* Ub = Ut2 + (size_t)b * 12 * DM_ * 32;
    f32x4 zero = {0.f, 0.f, 0.f, 0.f};
    f32x4 acc[4][4];
    #pragma unroll
    for (int si = 0; si < 4; si++)
        #pragma unroll
        for (int ej = 0; ej < 4; ej++) acc[si][ej] = zero;

    auto stage = [&](int kk, int bufsel) {
        const unsigned short* Pslab = Pb + (size_t)kk * S_ * 32;
        const unsigned short* Uslab = Ub + (size_t)kk * DM_ * 32;
        #pragma unroll
        for (int i = 0; i < 2; i++) {
            int idx = i * 256 + tid;
            int r = idx >> 2, m = (idx & 3) ^ ((r >> 1) & 3);
            gload16(Pslab + ((size_t)s0 + r) * 32 + m * 8, (char*)Plds + bufsel * 8192 + idx * 16);
            gload16(Uslab + ((size_t)e0 + r) * 32 + m * 8, (char*)Ulds + bufsel * 8192 + idx * 16);
        }
    };
    auto compute = [&](int cur) {
        bf16x8 uf[4], pf[4];
        #pragma unroll
        for (int ej = 0; ej < 4; ej++)
            uf[ej] = *(const bf16x8*)&Ulds[cur * 4096 + (wr * 64 + ej * 16 + l15) * 32 + rdsw];
        #pragma unroll
        for (int si = 0; si < 4; si++)
            pf[si] = *(const bf16x8*)&Plds[cur * 4096 + (wc * 64 + si * 16 + l15) * 32 + rdsw];
        __builtin_amdgcn_s_setprio(1);
        #pragma unroll
        for (int si = 0; si < 4; si++)
            #pragma unroll
            for (int ej = 0; ej < 4; ej++)
                acc[si][ej] = __builtin_amdgcn_mfma_f32_16x16x32_bf16(uf[ej], pf[si], acc[si][ej], 0, 0, 0);
        __builtin_amdgcn_s_setprio(0);
    };
    auto PITER = [&](int kk, int cur, int tgt) {
        stage(kk + 2, tgt);
        WAIT_VM(8);
        S_BARRIER();
        compute(cur);
        WAIT_LGKM0();
        S_BARRIER();
    };

    stage(0, 0); stage(1, 1);
    for (int k0 = 0; k0 < 9; k0 += 3) {
        PITER(k0 + 0, 0, 2); PITER(k0 + 1, 1, 0); PITER(k0 + 2, 2, 1);
    }
    PITER(9, 0, 2);
    WAIT_VM(4); S_BARRIER(); compute(1); WAIT_LGKM0(); S_BARRIER();
    WAIT_VM(0); S_BARRIER(); compute(2);

    float4 b4[4];
    #pragma unroll
    for (int ej = 0; ej < 4; ej++)
        b4[ej] = *(const float4*)(bo + e0 + wr * 64 + ej * 16 + l4 * 4);
    #pragma unroll
    for (int si = 0; si < 4; si++) {
        int srow = s0 + wc * 64 + si * 16 + l15;
        #pragma unroll
        for (int ej = 0; ej < 4; ej++) {
            int ecol = e0 + wr * 64 + ej * 16 + l4 * 4;
            size_t off = ((size_t)b * S_ + srow) * DM_ + ecol;
            float4 h4 = *(const float4*)(hid + off);
            f32x4 a = acc[si][ej];
            float4 o4;
            o4.x = a[0] + b4[ej].x + h4.x;
            o4.y = a[1] + b4[ej].y + h4.y;
            o4.z = a[2] + b4[ej].z + h4.z;
            o4.w = a[3] + b4[ej].w + h4.w;
            *(float4*)(out + off) = o4;
        }
    }
}

extern "C" void kernel_launch(void* const* d_in, const int* in_sizes, int n_in,
                              void* d_out, int out_size, void* d_ws, size_t ws_size,
                              hipStream_t stream) {
    const float* hid  = (const float*)d_in[0];
    const float* enc  = (const float*)d_in[1];
    const float* wq   = (const float*)d_in[2];
    const float* wk   = (const float*)d_in[3];
    const float* wv   = (const float*)d_in[4];
    const float* wkd  = (const float*)d_in[5];
    const float* wvd  = (const float*)d_in[6];
    const float* wout = (const float*)d_in[7];
    const float* bo   = (const float*)d_in[8];
    float* out = (float*)d_out;

    char* ws = (char*)d_ws;
    unsigned short* At2    = (unsigned short*)(ws);               // 15,728,640
    unsigned short* Ut2    = (unsigned short*)(ws + 15728640);    // 15,728,640
    unsigned short* KV     = (unsigned short*)(ws + 31457280);    //  3,932,160
    unsigned short* wq_bf  = (unsigned short*)(ws + 35389440);    //  3,276,800
    unsigned short* woutT  = (unsigned short*)(ws + 38666240);    //  3,276,800
    unsigned short* wTk    = (unsigned short*)(ws + 41943040);    //  1,966,080
    unsigned short* wTv    = (unsigned short*)(ws + 43909120);    //  1,966,080
    unsigned short* wTkd   = (unsigned short*)(ws + 45875200);    //  1,966,080
    unsigned short* wTvd   = (unsigned short*)(ws + 47841280);    //  1,966,080 (end 49,807,360)
    unsigned short* P2     = (unsigned short*)(ws + 35389440);    // 50,331,648 — overlaps dead weights

    k_prep<<<7040, 256, 0, stream>>>(wq, wk, wv, wkd, wvd, wout,
                                     wq_bf, wTk, wTv, wTkd, wTvd, woutT);
    k_projM<<<480, 256, 0, stream>>>(enc, wTk, wTv, wTkd, wTvd, KV);
    k_au<<<768, 256, 0, stream>>>(KV, wq_bf, woutT, At2, Ut2);
    k_scores8<<<512, 256, 0, stream>>>(hid, At2, P2);
    k_pv4<<<5120, 256, 0, stream>>>(P2, Ut2, hid, bo, out);
}

// Round 13
// 404.959 us; speedup vs baseline: 1.3727x; 1.3727x over previous
//
#include <hip/hip_runtime.h>
#include <hip/hip_bf16.h>

#define B_ 16
#define S_ 4096
#define DM_ 1280
#define DC_ 768
#define NC_ 384
#define SCALE_ 0.07905694150420949f

typedef __attribute__((ext_vector_type(8))) short bf16x8;
typedef __attribute__((ext_vector_type(4))) float f32x4;
typedef __attribute__((ext_vector_type(4))) unsigned short u16x4;

#define S_BARRIER() asm volatile("s_barrier" ::: "memory")
#define WAIT_VM(n) asm volatile("s_waitcnt vmcnt(" #n ")" ::: "memory")
#define WAIT_LGKM0() asm volatile("s_waitcnt lgkmcnt(0)" ::: "memory")

__device__ __forceinline__ unsigned short f2bf(float f) {
    unsigned int u = __builtin_bit_cast(unsigned int, f);
    u = (u + 0x7FFFu + ((u >> 16) & 1u)) >> 16;
    return (unsigned short)u;
}

__device__ __forceinline__ bf16x8 pack8(float4 x0, float4 x1) {
    bf16x8 a;
    a[0] = __builtin_bit_cast(short, __float2bfloat16(x0.x));
    a[1] = __builtin_bit_cast(short, __float2bfloat16(x0.y));
    a[2] = __builtin_bit_cast(short, __float2bfloat16(x0.z));
    a[3] = __builtin_bit_cast(short, __float2bfloat16(x0.w));
    a[4] = __builtin_bit_cast(short, __float2bfloat16(x1.x));
    a[5] = __builtin_bit_cast(short, __float2bfloat16(x1.y));
    a[6] = __builtin_bit_cast(short, __float2bfloat16(x1.z));
    a[7] = __builtin_bit_cast(short, __float2bfloat16(x1.w));
    return a;
}

__device__ __forceinline__ void gload16(const void* g, void* l) {
    __builtin_amdgcn_global_load_lds(
        (const __attribute__((address_space(1))) void*)g,
        (__attribute__((address_space(3))) void*)l, 16, 0, 0);
}

// ---------- merged prep: wq cvt + 5 transpose/cvt ----------
__device__ __forceinline__ void tcvt_body(const float* __restrict__ in,
                                          unsigned short* __restrict__ out,
                                          int R, int C, int bx, int by, int tid) {
    __shared__ float tile[32][33];
    int c0 = bx * 32, r0 = by * 32;
    int tx = tid & 31, ty = tid >> 5;
    for (int i = ty; i < 32; i += 8)
        tile[i][tx] = in[(size_t)(r0 + i) * C + c0 + tx];
    __syncthreads();
    for (int i = ty; i < 32; i += 8)
        out[(size_t)(c0 + i) * R + r0 + tx] = f2bf(tile[tx][i]);
}

__global__ __launch_bounds__(256)
void k_prep(const float* __restrict__ wq, const float* __restrict__ wk,
            const float* __restrict__ wv, const float* __restrict__ wkd,
            const float* __restrict__ wvd, const float* __restrict__ wout,
            unsigned short* __restrict__ wq_bf, unsigned short* __restrict__ wTk,
            unsigned short* __restrict__ wTv, unsigned short* __restrict__ wTkd,
            unsigned short* __restrict__ wTvd, unsigned short* __restrict__ woutT) {
    int bid = blockIdx.x, tid = threadIdx.x;
    if (bid < 1600) {
        int i = bid * 256 + tid;
        float4 v = ((const float4*)wq)[i];
        u16x4 o = { f2bf(v.x), f2bf(v.y), f2bf(v.z), f2bf(v.w) };
        ((u16x4*)wq_bf)[i] = o;
    } else if (bid < 2560) {
        int r = bid - 1600; tcvt_body(wk,  wTk,  DC_, DM_, r % 40, r / 40, tid);
    } else if (bid < 3520) {
        int r = bid - 2560; tcvt_body(wv,  wTv,  DC_, DM_, r % 40, r / 40, tid);
    } else if (bid < 4480) {
        int r = bid - 3520; tcvt_body(wkd, wTkd, DC_, DM_, r % 40, r / 40, tid);
    } else if (bid < 5440) {
        int r = bid - 4480; tcvt_body(wvd, wTvd, DC_, DM_, r % 40, r / 40, tid);
    } else {
        int r = bid - 5440; tcvt_body(wout, woutT, DM_, DM_, r % 40, r / 40, tid);
    }
}

// ---------- K/V projections via MFMA ----------
__global__ __launch_bounds__(256)
void k_projM(const float* __restrict__ enc,
             const unsigned short* __restrict__ wTk, const unsigned short* __restrict__ wTv,
             const unsigned short* __restrict__ wTkd, const unsigned short* __restrict__ wTvd,
             unsigned short* __restrict__ KV) {
    int bid = blockIdx.x;
    int j = bid / 80, rem = bid % 80, b = rem / 5, nt = rem % 5;
    int tid = threadIdx.x, w = tid >> 6, l = tid & 63, l15 = l & 15, l4 = l >> 4;
    int tok0 = (j < 2) ? 16 : ((j < 4) ? 0 : 32);
    const unsigned short* wT = (j == 0) ? wTk : (j == 1) ? wTv : (j == 2 || j == 4) ? wTkd : wTvd;
    const float* ap = enc + ((size_t)(b * 48 + tok0 + l15)) * DC_;
    f32x4 zero = {0.f, 0.f, 0.f, 0.f};
    f32x4 acc[4];
    #pragma unroll
    for (int t = 0; t < 4; t++) acc[t] = zero;
    for (int kk = 0; kk < 24; kk++) {
        const float4* hp = (const float4*)(ap + kk * 32 + l4 * 8);
        bf16x8 af = pack8(hp[0], hp[1]);
        #pragma unroll
        for (int t = 0; t < 4; t++) {
            int n0 = nt * 256 + w * 64 + t * 16;
            bf16x8 bf = *(const bf16x8*)(wT + (size_t)(n0 + l15) * DC_ + kk * 32 + l4 * 8);
            acc[t] = __builtin_amdgcn_mfma_f32_16x16x32_bf16(af, bf, acc[t], 0, 0, 0);
        }
    }
    #pragma unroll
    for (int t = 0; t < 4; t++) {
        int e = nt * 256 + w * 64 + t * 16 + l15;
        #pragma unroll
        for (int r = 0; r < 4; r++)
            KV[((size_t)(j * 16 + b) * 16 + l4 * 4 + r) * DM_ + e] = f2bf(acc[t][r]);
    }
}

// ---------- merged A/U build; outputs kk-major layouts ----------
// At2[b][40][384c][32d], Ut2[b][12][1280e][32c]
__global__ __launch_bounds__(256)
void k_au(const unsigned short* __restrict__ KV, const unsigned short* __restrict__ wqbf,
          const unsigned short* __restrict__ woutT,
          unsigned short* __restrict__ At2, unsigned short* __restrict__ Ut2) {
    int bid0 = blockIdx.x;
    bool isA = bid0 < 384;
    int bid = isA ? bid0 : bid0 - 384;
    int b = bid & 15, r_ = bid >> 4, x = r_ >> 3, h = r_ & 7;
    int tid = threadIdx.x, w = tid >> 6, l = tid & 63, l15 = l & 15, l4 = l >> 4;
    int xh = x * 8 + h;
    int jrow = isA ? (2 * x) : (2 * x + 1);
    const unsigned short* wmat = isA ? wqbf : woutT;
    float postscale = isA ? SCALE_ : ((x == 2) ? 1.0f : 0.5f);
    bf16x8 bfr[5];
    #pragma unroll
    for (int kk = 0; kk < 5; kk++)
        bfr[kk] = *(const bf16x8*)(KV + ((size_t)(jrow * 16 + b) * 16 + l15) * DM_ + h * 160 + kk * 32 + l4 * 8);
    f32x4 zero = {0.f, 0.f, 0.f, 0.f};
    for (int tt = 0; tt < 20; tt++) {
        int d0 = w * 320 + tt * 16;
        f32x4 acc = zero;
        if (isA) {
            #pragma unroll
            for (int kk = 0; kk < 5; kk++) {
                bf16x8 af = *(const bf16x8*)(wmat + (size_t)(d0 + l15) * DM_ + h * 160 + kk * 32 + l4 * 8);
                acc = __builtin_amdgcn_mfma_f32_16x16x32_bf16(af, bfr[kk], acc, 0, 0, 0);
            }
            int c = xh * 16 + l15;
            u16x4 pk;
            #pragma unroll
            for (int r = 0; r < 4; r++) pk[r] = f2bf(acc[r] * postscale);
            *(u16x4*)(At2 + ((size_t)(b * 40 + (d0 >> 5)) * NC_ + c) * 32 + (d0 & 31) + l4 * 4) = pk;
        } else {
            #pragma unroll
            for (int kk = 0; kk < 5; kk++) {
                bf16x8 af = *(const bf16x8*)(wmat + (size_t)(d0 + l15) * DM_ + h * 160 + kk * 32 + l4 * 8);
                acc = __builtin_amdgcn_mfma_f32_16x16x32_bf16(bfr[kk], af, acc, 0, 0, 0);
            }
            int e = d0 + l15;
            u16x4 pk;
            #pragma unroll
            for (int r = 0; r < 4; r++) pk[r] = f2bf(acc[r] * postscale);
            *(u16x4*)(Ut2 + ((size_t)(b * 12 + (xh >> 1)) * DM_ + e) * 32 + (xh & 1) * 16 + l4 * 4) = pk;
        }
    }
}

// ---------- scores: uniform gload_lds; A depth-1 dbuf, H depth-2 tbuf (R11-proven) ----------
__global__ __launch_bounds__(256, 2)
void k_scores7(const float* __restrict__ hid, const unsigned short* __restrict__ At2,
               unsigned short* __restrict__ P2) {
    __shared__ char smem[73728];                 // A 2x24KB @0; H 3x8KB @48K; P reuses 0..48K
    unsigned short* Apnl = (unsigned short*)smem;
    char* Hlds = smem + 49152;
    int bid = blockIdx.x;
    int orig = (bid & 7) * 128 + (bid >> 3);     // XCD-chunked
    int b = orig >> 6, st = orig & 63;
    int s0 = st * 64;
    int tid = threadIdx.x, w = tid >> 6, l = tid & 63, l15 = l & 15, l4 = l >> 4;
    int rdsw = (l4 ^ ((l15 >> 1) & 3)) * 8;
    const unsigned short* Ab = At2 + (size_t)b * 40 * NC_ * 32;
    const float* hsrc = hid + ((size_t)b * S_ + s0) * DM_;
    f32x4 zero = {0.f, 0.f, 0.f, 0.f};
    f32x4 acc[4][6];
    #pragma unroll
    for (int si = 0; si < 4; si++)
        #pragma unroll
        for (int cj = 0; cj < 6; cj++) acc[si][cj] = zero;

    auto stageA = [&](int kk, int ab) {          // 6 gload_lds
        const unsigned short* slab = Ab + (size_t)kk * (NC_ * 32);
        #pragma unroll
        for (int i = 0; i < 6; i++) {
            int idx = i * 256 + tid;
            int c = idx >> 2, m = (idx & 3) ^ ((c >> 1) & 3);
            gload16(slab + (size_t)c * 32 + m * 8, smem + ab * 24576 + idx * 16);
        }
    };
    auto stageH = [&](int kk, int hb) {          // 2 gload_lds
        #pragma unroll
        for (int i = 0; i < 2; i++) {
            int idx = i * 256 + tid;
            int r = idx >> 3, sg = (idx & 7) ^ (r & 7);
            gload16(hsrc + (size_t)r * DM_ + kk * 32 + sg * 4, Hlds + hb * 8192 + idx * 16);
        }
    };
    auto compute = [&](int ab, int hb) {
        bf16x8 hpk[4];
        #pragma unroll
        for (int si = 0; si < 4; si++) {
            int r = si * 16 + l15;
            float4 lo = *(const float4*)(Hlds + hb * 8192 + r * 128 + (((2 * l4) ^ (l15 & 7)) * 16));
            float4 hi = *(const float4*)(Hlds + hb * 8192 + r * 128 + (((2 * l4 + 1) ^ (l15 & 7)) * 16));
            hpk[si] = pack8(lo, hi);
        }
        __builtin_amdgcn_s_setprio(1);
        #pragma unroll
        for (int cj = 0; cj < 6; cj++) {
            bf16x8 af = *(const bf16x8*)&Apnl[ab * 12288 + (w * 96 + cj * 16 + l15) * 32 + rdsw];
            #pragma unroll
            for (int si = 0; si < 4; si++)
                acc[si][cj] = __builtin_amdgcn_mfma_f32_16x16x32_bf16(af, hpk[si], acc[si][cj], 0, 0, 0);
        }
        __builtin_amdgcn_s_setprio(0);
    };
    auto SITER = [&](int kk) {
        stageA(kk + 1, (kk + 1) & 1);
        stageH(kk + 2, (kk + 2) % 3);
        WAIT_VM(10);
        S_BARRIER();
        compute(kk & 1, kk % 3);
        WAIT_LGKM0();
        S_BARRIER();
    };

    stageA(0, 0); stageH(0, 0); stageH(1, 1);    // queue = 10
    for (int k0 = 0; k0 < 36; k0 += 6) {
        SITER(k0 + 0); SITER(k0 + 1); SITER(k0 + 2);
        SITER(k0 + 3); SITER(k0 + 4); SITER(k0 + 5);
    }
    SITER(36); SITER(37);
    stageA(39, 1);
    WAIT_VM(8);
    S_BARRIER();
    compute(0, 38 % 3);
    WAIT_LGKM0();
    S_BARRIER();
    WAIT_VM(0);
    S_BARRIER();
    compute(1, 39 % 3);
    WAIT_LGKM0();
    S_BARRIER();

    // softmax per 16-c group; P into LDS [kk2][64 s][32 c] with chunk-XOR on (s&3)
    #pragma unroll
    for (int si = 0; si < 4; si++) {
        int s_l = si * 16 + l15;
        #pragma unroll
        for (int cj = 0; cj < 6; cj++) {
            float v0 = acc[si][cj][0], v1 = acc[si][cj][1], v2 = acc[si][cj][2], v3 = acc[si][cj][3];
            float mx = fmaxf(fmaxf(v0, v1), fmaxf(v2, v3));
            mx = fmaxf(mx, __shfl_xor(mx, 16));
            mx = fmaxf(mx, __shfl_xor(mx, 32));
            float e0 = __expf(v0 - mx), e1 = __expf(v1 - mx), e2 = __expf(v2 - mx), e3 = __expf(v3 - mx);
            float sm = e0 + e1 + e2 + e3;
            sm += __shfl_xor(sm, 16);
            sm += __shfl_xor(sm, 32);
            float rs = 1.0f / sm;
            u16x4 pk = { f2bf(e0 * rs), f2bf(e1 * rs), f2bf(e2 * rs), f2bf(e3 * rs) };
            int c = w * 96 + cj * 16 + l4 * 4;
            int chunk = ((c & 31) >> 3) ^ (s_l & 3);
            *(u16x4*)(smem + (c >> 5) * 4096 + s_l * 64 + chunk * 16 + (l4 & 1) * 8) = pk;
        }
    }
    __syncthreads();

    unsigned short* P2b = P2 + (size_t)b * 12 * S_ * 32;
    #pragma unroll
    for (int i = 0; i < 12; i++) {
        int sl = tid >> 2, m = tid & 3;
        uint4 v = *(const uint4*)(smem + i * 4096 + sl * 64 + ((m ^ (sl & 3)) * 16));
        *(uint4*)(P2b + ((size_t)i * S_ + s0 + sl) * 32 + m * 8) = v;
    }
}

// ---------- PV: K-step 64 (2 slabs/stage), dbuf, 6 frames, uniform gload_lds ----------
__global__ __launch_bounds__(256, 2)
void k_pv5(const unsigned short* __restrict__ P2, const unsigned short* __restrict__ Ut2,
           const float* __restrict__ hid, const float* __restrict__ bo,
           float* __restrict__ out) {
    __shared__ unsigned short Plds[2][2][4096];  // [buf][sub][8KB]
    __shared__ unsigned short Ulds[2][2][4096];
    int bid = blockIdx.x;
    int orig = (bid & 7) * 640 + (bid >> 3);     // XCD-chunked
    int b = orig / 320, rem = orig % 320;
    int st = rem / 10, ec = rem % 10;
    int s0 = st * 128, e0 = ec * 128;
    int tid = threadIdx.x, w = tid >> 6, l = tid & 63, l15 = l & 15, l4 = l >> 4;
    int wr = w >> 1, wc = w & 1;
    int rdsw = (l4 ^ ((l15 >> 1) & 3)) * 8;
    const unsigned short* Pb = P2 + (size_t)b * 12 * S_ * 32;
    const unsigned short* Ub = Ut2 + (size_t)b * 12 * DM_ * 32;
    f32x4 zero = {0.f, 0.f, 0.f, 0.f};
    f32x4 acc[4][4];
    #pragma unroll
    for (int si = 0; si < 4; si++)
        #pragma unroll
        for (int ej = 0; ej < 4; ej++) acc[si][ej] = zero;

    // stage K-step kk2 (= kk pair 2*kk2, 2*kk2+1): 8 uniform gload_lds
    auto stage = [&](int kk2, int buf) {
        #pragma unroll
        for (int sub = 0; sub < 2; sub++) {
            int kk = kk2 * 2 + sub;
            const unsigned short* Pslab = Pb + (size_t)kk * S_ * 32;
            const unsigned short* Uslab = Ub + (size_t)kk * DM_ * 32;
            #pragma unroll
            for (int i = 0; i < 2; i++) {
                int idx = i * 256 + tid;
                int r = idx >> 2, m = (idx & 3) ^ ((r >> 1) & 3);
                gload16(Pslab + ((size_t)s0 + r) * 32 + m * 8, (char*)&Plds[buf][sub][0] + idx * 16);
                gload16(Uslab + ((size_t)e0 + r) * 32 + m * 8, (char*)&Ulds[buf][sub][0] + idx * 16);
            }
        }
    };
    auto compute = [&](int buf) {
        #pragma unroll
        for (int sub = 0; sub < 2; sub++) {
            bf16x8 uf[4], pf[4];
            #pragma unroll
            for (int ej = 0; ej < 4; ej++)
                uf[ej] = *(const bf16x8*)&Ulds[buf][sub][(wr * 64 + ej * 16 + l15) * 32 + rdsw];
            #pragma unroll
            for (int si = 0; si < 4; si++)
                pf[si] = *(const bf16x8*)&Plds[buf][sub][(wc * 64 + si * 16 + l15) * 32 + rdsw];
            __builtin_amdgcn_s_setprio(1);
            #pragma unroll
            for (int si = 0; si < 4; si++)
                #pragma unroll
                for (int ej = 0; ej < 4; ej++)
                    acc[si][ej] = __builtin_amdgcn_mfma_f32_16x16x32_bf16(uf[ej], pf[si], acc[si][ej], 0, 0, 0);
            __builtin_amdgcn_s_setprio(0);
        }
    };

    stage(0, 0);                                 // queue = 8
    for (int kk2 = 0; kk2 < 5; kk2++) {
        stage(kk2 + 1, (kk2 + 1) & 1);           // +8 -> 16
        WAIT_VM(8);                              // drain stage kk2
        S_BARRIER();
        compute(kk2 & 1);
        WAIT_LGKM0();
        S_BARRIER();
    }
    WAIT_VM(0);
    S_BARRIER();
    compute(1);                                  // kk2=5 in buf 1

    float4 b4[4];
    #pragma unroll
    for (int ej = 0; ej < 4; ej++)
        b4[ej] = *(const float4*)(bo + e0 + wr * 64 + ej * 16 + l4 * 4);
    #pragma unroll
    for (int si = 0; si < 4; si++) {
        int srow = s0 + wc * 64 + si * 16 + l15;
        #pragma unroll
        for (int ej = 0; ej < 4; ej++) {
            int ecol = e0 + wr * 64 + ej * 16 + l4 * 4;
            size_t off = ((size_t)b * S_ + srow) * DM_ + ecol;
            float4 h4 = *(const float4*)(hid + off);
            f32x4 a = acc[si][ej];
            float4 o4;
            o4.x = a[0] + b4[ej].x + h4.x;
            o4.y = a[1] + b4[ej].y + h4.y;
            o4.z = a[2] + b4[ej].z + h4.z;
            o4.w = a[3] + b4[ej].w + h4.w;
            *(float4*)(out + off) = o4;
        }
    }
}

extern "C" void kernel_launch(void* const* d_in, const int* in_sizes, int n_in,
                              void* d_out, int out_size, void* d_ws, size_t ws_size,
                              hipStream_t stream) {
    const float* hid  = (const float*)d_in[0];
    const float* enc  = (const float*)d_in[1];
    const float* wq   = (const float*)d_in[2];
    const float* wk   = (const float*)d_in[3];
    const float* wv   = (const float*)d_in[4];
    const float* wkd  = (const float*)d_in[5];
    const float* wvd  = (const float*)d_in[6];
    const float* wout = (const float*)d_in[7];
    const float* bo   = (const float*)d_in[8];
    float* out = (float*)d_out;

    char* ws = (char*)d_ws;
    unsigned short* At2    = (unsigned short*)(ws);               // 15,728,640
    unsigned short* Ut2    = (unsigned short*)(ws + 15728640);    // 15,728,640
    unsigned short* KV     = (unsigned short*)(ws + 31457280);    //  3,932,160
    unsigned short* wq_bf  = (unsigned short*)(ws + 35389440);    //  3,276,800
    unsigned short* woutT  = (unsigned short*)(ws + 38666240);    //  3,276,800
    unsigned short* wTk    = (unsigned short*)(ws + 41943040);    //  1,966,080
    unsigned short* wTv    = (unsigned short*)(ws + 43909120);    //  1,966,080
    unsigned short* wTkd   = (unsigned short*)(ws + 45875200);    //  1,966,080
    unsigned short* wTvd   = (unsigned short*)(ws + 47841280);    //  1,966,080 (end 49,807,360)
    unsigned short* P2     = (unsigned short*)(ws + 35389440);    // 50,331,648 — overlaps dead weights

    k_prep<<<7040, 256, 0, stream>>>(wq, wk, wv, wkd, wvd, wout,
                                     wq_bf, wTk, wTv, wTkd, wTvd, woutT);
    k_projM<<<480, 256, 0, stream>>>(enc, wTk, wTv, wTkd, wTvd, KV);
    k_au<<<768, 256, 0, stream>>>(KV, wq_bf, woutT, At2, Ut2);
    k_scores7<<<1024, 256, 0, stream>>>(hid, At2, P2);
    k_pv5<<<5120, 256, 0, stream>>>(P2, Ut2, hid, bo, out);
}

// Round 14
// 393.800 us; speedup vs baseline: 1.4116x; 1.0283x over previous
//
#include <hip/hip_runtime.h>
#include <hip/hip_bf16.h>

#define B_ 16
#define S_ 4096
#define DM_ 1280
#define DC_ 768
#define NC_ 384
#define SCALE_ 0.07905694150420949f

typedef __attribute__((ext_vector_type(8))) short bf16x8;
typedef __attribute__((ext_vector_type(4))) float f32x4;
typedef __attribute__((ext_vector_type(4))) unsigned short u16x4;

#define S_BARRIER() asm volatile("s_barrier" ::: "memory")
#define WAIT_VM(n) asm volatile("s_waitcnt vmcnt(" #n ")" ::: "memory")
#define WAIT_LGKM0() asm volatile("s_waitcnt lgkmcnt(0)" ::: "memory")

__device__ __forceinline__ unsigned short f2bf(float f) {
    unsigned int u = __builtin_bit_cast(unsigned int, f);
    u = (u + 0x7FFFu + ((u >> 16) & 1u)) >> 16;
    return (unsigned short)u;
}

__device__ __forceinline__ bf16x8 pack8(float4 x0, float4 x1) {
    bf16x8 a;
    a[0] = __builtin_bit_cast(short, __float2bfloat16(x0.x));
    a[1] = __builtin_bit_cast(short, __float2bfloat16(x0.y));
    a[2] = __builtin_bit_cast(short, __float2bfloat16(x0.z));
    a[3] = __builtin_bit_cast(short, __float2bfloat16(x0.w));
    a[4] = __builtin_bit_cast(short, __float2bfloat16(x1.x));
    a[5] = __builtin_bit_cast(short, __float2bfloat16(x1.y));
    a[6] = __builtin_bit_cast(short, __float2bfloat16(x1.z));
    a[7] = __builtin_bit_cast(short, __float2bfloat16(x1.w));
    return a;
}

__device__ __forceinline__ void gload16(const void* g, void* l) {
    __builtin_amdgcn_global_load_lds(
        (const __attribute__((address_space(1))) void*)g,
        (__attribute__((address_space(3))) void*)l, 16, 0, 0);
}

// ---------- merged prep: wq cvt + 5 transpose/cvt ----------
__device__ __forceinline__ void tcvt_body(const float* __restrict__ in,
                                          unsigned short* __restrict__ out,
                                          int R, int C, int bx, int by, int tid) {
    __shared__ float tile[32][33];
    int c0 = bx * 32, r0 = by * 32;
    int tx = tid & 31, ty = tid >> 5;
    for (int i = ty; i < 32; i += 8)
        tile[i][tx] = in[(size_t)(r0 + i) * C + c0 + tx];
    __syncthreads();
    for (int i = ty; i < 32; i += 8)
        out[(size_t)(c0 + i) * R + r0 + tx] = f2bf(tile[tx][i]);
}

__global__ __launch_bounds__(256)
void k_prep(const float* __restrict__ wq, const float* __restrict__ wk,
            const float* __restrict__ wv, const float* __restrict__ wkd,
            const float* __restrict__ wvd, const float* __restrict__ wout,
            unsigned short* __restrict__ wq_bf, unsigned short* __restrict__ wTk,
            unsigned short* __restrict__ wTv, unsigned short* __restrict__ wTkd,
            unsigned short* __restrict__ wTvd, unsigned short* __restrict__ woutT) {
    int bid = blockIdx.x, tid = threadIdx.x;
    if (bid < 1600) {
        int i = bid * 256 + tid;
        float4 v = ((const float4*)wq)[i];
        u16x4 o = { f2bf(v.x), f2bf(v.y), f2bf(v.z), f2bf(v.w) };
        ((u16x4*)wq_bf)[i] = o;
    } else if (bid < 2560) {
        int r = bid - 1600; tcvt_body(wk,  wTk,  DC_, DM_, r % 40, r / 40, tid);
    } else if (bid < 3520) {
        int r = bid - 2560; tcvt_body(wv,  wTv,  DC_, DM_, r % 40, r / 40, tid);
    } else if (bid < 4480) {
        int r = bid - 3520; tcvt_body(wkd, wTkd, DC_, DM_, r % 40, r / 40, tid);
    } else if (bid < 5440) {
        int r = bid - 4480; tcvt_body(wvd, wTvd, DC_, DM_, r % 40, r / 40, tid);
    } else {
        int r = bid - 5440; tcvt_body(wout, woutT, DM_, DM_, r % 40, r / 40, tid);
    }
}

// ---------- K/V projections via MFMA ----------
__global__ __launch_bounds__(256)
void k_projM(const float* __restrict__ enc,
             const unsigned short* __restrict__ wTk, const unsigned short* __restrict__ wTv,
             const unsigned short* __restrict__ wTkd, const unsigned short* __restrict__ wTvd,
             unsigned short* __restrict__ KV) {
    int bid = blockIdx.x;
    int j = bid / 80, rem = bid % 80, b = rem / 5, nt = rem % 5;
    int tid = threadIdx.x, w = tid >> 6, l = tid & 63, l15 = l & 15, l4 = l >> 4;
    int tok0 = (j < 2) ? 16 : ((j < 4) ? 0 : 32);
    const unsigned short* wT = (j == 0) ? wTk : (j == 1) ? wTv : (j == 2 || j == 4) ? wTkd : wTvd;
    const float* ap = enc + ((size_t)(b * 48 + tok0 + l15)) * DC_;
    f32x4 zero = {0.f, 0.f, 0.f, 0.f};
    f32x4 acc[4];
    #pragma unroll
    for (int t = 0; t < 4; t++) acc[t] = zero;
    for (int kk = 0; kk < 24; kk++) {
        const float4* hp = (const float4*)(ap + kk * 32 + l4 * 8);
        bf16x8 af = pack8(hp[0], hp[1]);
        #pragma unroll
        for (int t = 0; t < 4; t++) {
            int n0 = nt * 256 + w * 64 + t * 16;
            bf16x8 bf = *(const bf16x8*)(wT + (size_t)(n0 + l15) * DC_ + kk * 32 + l4 * 8);
            acc[t] = __builtin_amdgcn_mfma_f32_16x16x32_bf16(af, bf, acc[t], 0, 0, 0);
        }
    }
    #pragma unroll
    for (int t = 0; t < 4; t++) {
        int e = nt * 256 + w * 64 + t * 16 + l15;
        #pragma unroll
        for (int r = 0; r < 4; r++)
            KV[((size_t)(j * 16 + b) * 16 + l4 * 4 + r) * DM_ + e] = f2bf(acc[t][r]);
    }
}

// ---------- merged A/U build; outputs kk-major layouts ----------
// At2[b][40][384c][32d], Ut2[b][12][1280e][32c]
__global__ __launch_bounds__(256)
void k_au(const unsigned short* __restrict__ KV, const unsigned short* __restrict__ wqbf,
          const unsigned short* __restrict__ woutT,
          unsigned short* __restrict__ At2, unsigned short* __restrict__ Ut2) {
    int bid0 = blockIdx.x;
    bool isA = bid0 < 384;
    int bid = isA ? bid0 : bid0 - 384;
    int b = bid & 15, r_ = bid >> 4, x = r_ >> 3, h = r_ & 7;
    int tid = threadIdx.x, w = tid >> 6, l = tid & 63, l15 = l & 15, l4 = l >> 4;
    int xh = x * 8 + h;
    int jrow = isA ? (2 * x) : (2 * x + 1);
    const unsigned short* wmat = isA ? wqbf : woutT;
    float postscale = isA ? SCALE_ : ((x == 2) ? 1.0f : 0.5f);
    bf16x8 bfr[5];
    #pragma unroll
    for (int kk = 0; kk < 5; kk++)
        bfr[kk] = *(const bf16x8*)(KV + ((size_t)(jrow * 16 + b) * 16 + l15) * DM_ + h * 160 + kk * 32 + l4 * 8);
    f32x4 zero = {0.f, 0.f, 0.f, 0.f};
    for (int tt = 0; tt < 20; tt++) {
        int d0 = w * 320 + tt * 16;
        f32x4 acc = zero;
        if (isA) {
            #pragma unroll
            for (int kk = 0; kk < 5; kk++) {
                bf16x8 af = *(const bf16x8*)(wmat + (size_t)(d0 + l15) * DM_ + h * 160 + kk * 32 + l4 * 8);
                acc = __builtin_amdgcn_mfma_f32_16x16x32_bf16(af, bfr[kk], acc, 0, 0, 0);
            }
            int c = xh * 16 + l15;
            u16x4 pk;
            #pragma unroll
            for (int r = 0; r < 4; r++) pk[r] = f2bf(acc[r] * postscale);
            *(u16x4*)(At2 + ((size_t)(b * 40 + (d0 >> 5)) * NC_ + c) * 32 + (d0 & 31) + l4 * 4) = pk;
        } else {
            #pragma unroll
            for (int kk = 0; kk < 5; kk++) {
                bf16x8 af = *(const bf16x8*)(wmat + (size_t)(d0 + l15) * DM_ + h * 160 + kk * 32 + l4 * 8);
                acc = __builtin_amdgcn_mfma_f32_16x16x32_bf16(bfr[kk], af, acc, 0, 0, 0);
            }
            int e = d0 + l15;
            u16x4 pk;
            #pragma unroll
            for (int r = 0; r < 4; r++) pk[r] = f2bf(acc[r] * postscale);
            *(u16x4*)(Ut2 + ((size_t)(b * 12 + (xh >> 1)) * DM_ + e) * 32 + (xh & 1) * 16 + l4 * 4) = pk;
        }
    }
}

// ---------- FUSED: scores (scores7) -> softmax -> P in LDS -> PV + epilogue ----------
__global__ __launch_bounds__(256, 2)
void k_fused(const float* __restrict__ hid, const unsigned short* __restrict__ At2,
             const unsigned short* __restrict__ Ut2, const float* __restrict__ bo,
             float* __restrict__ out) {
    __shared__ char smem[81920];                 // ph1: A 2x24KB @0, H 3x8KB @48K
                                                 // ph2: P 48KB @0,   U 2x16KB @48K
    unsigned short* Apnl = (unsigned short*)smem;
    char* Hlds = smem + 49152;
    unsigned short* Ulds2 = (unsigned short*)(smem + 49152);
    int bid = blockIdx.x;
    int orig = (bid & 7) * 128 + (bid >> 3);     // XCD-chunked
    int b = orig >> 6, st = orig & 63;
    int s0 = st * 64;
    int tid = threadIdx.x, w = tid >> 6, l = tid & 63, l15 = l & 15, l4 = l >> 4;
    int rdsw = (l4 ^ ((l15 >> 1) & 3)) * 8;
    const unsigned short* Ab = At2 + (size_t)b * 40 * NC_ * 32;
    const float* hsrc = hid + ((size_t)b * S_ + s0) * DM_;
    f32x4 zero = {0.f, 0.f, 0.f, 0.f};

    // ===== phase 1: scores (R11-proven structure) =====
    {
        f32x4 acc[4][6];
        #pragma unroll
        for (int si = 0; si < 4; si++)
            #pragma unroll
            for (int cj = 0; cj < 6; cj++) acc[si][cj] = zero;

        auto stageA = [&](int kk, int ab) {
            const unsigned short* slab = Ab + (size_t)kk * (NC_ * 32);
            #pragma unroll
            for (int i = 0; i < 6; i++) {
                int idx = i * 256 + tid;
                int c = idx >> 2, m = (idx & 3) ^ ((c >> 1) & 3);
                gload16(slab + (size_t)c * 32 + m * 8, smem + ab * 24576 + idx * 16);
            }
        };
        auto stageH = [&](int kk, int hb) {
            #pragma unroll
            for (int i = 0; i < 2; i++) {
                int idx = i * 256 + tid;
                int r = idx >> 3, sg = (idx & 7) ^ (r & 7);
                gload16(hsrc + (size_t)r * DM_ + kk * 32 + sg * 4, Hlds + hb * 8192 + idx * 16);
            }
        };
        auto compute = [&](int ab, int hb) {
            bf16x8 hpk[4];
            #pragma unroll
            for (int si = 0; si < 4; si++) {
                int r = si * 16 + l15;
                float4 lo = *(const float4*)(Hlds + hb * 8192 + r * 128 + (((2 * l4) ^ (l15 & 7)) * 16));
                float4 hi = *(const float4*)(Hlds + hb * 8192 + r * 128 + (((2 * l4 + 1) ^ (l15 & 7)) * 16));
                hpk[si] = pack8(lo, hi);
            }
            __builtin_amdgcn_s_setprio(1);
            #pragma unroll
            for (int cj = 0; cj < 6; cj++) {
                bf16x8 af = *(const bf16x8*)&Apnl[ab * 12288 + (w * 96 + cj * 16 + l15) * 32 + rdsw];
                #pragma unroll
                for (int si = 0; si < 4; si++)
                    acc[si][cj] = __builtin_amdgcn_mfma_f32_16x16x32_bf16(af, hpk[si], acc[si][cj], 0, 0, 0);
            }
            __builtin_amdgcn_s_setprio(0);
        };
        auto SITER = [&](int kk) {
            stageA(kk + 1, (kk + 1) & 1);
            stageH(kk + 2, (kk + 2) % 3);
            WAIT_VM(10);
            S_BARRIER();
            compute(kk & 1, kk % 3);
            WAIT_LGKM0();
            S_BARRIER();
        };

        stageA(0, 0); stageH(0, 0); stageH(1, 1);
        for (int k0 = 0; k0 < 36; k0 += 6) {
            SITER(k0 + 0); SITER(k0 + 1); SITER(k0 + 2);
            SITER(k0 + 3); SITER(k0 + 4); SITER(k0 + 5);
        }
        SITER(36); SITER(37);
        stageA(39, 1);
        WAIT_VM(8);
        S_BARRIER();
        compute(0, 38 % 3);
        WAIT_LGKM0();
        S_BARRIER();
        WAIT_VM(0);
        S_BARRIER();
        compute(1, 39 % 3);
        WAIT_LGKM0();
        S_BARRIER();

        // softmax per 16-c group; P into LDS [kk2][64 s][32 c], chunk-XOR by (s&3)
        #pragma unroll
        for (int si = 0; si < 4; si++) {
            int s_l = si * 16 + l15;
            #pragma unroll
            for (int cj = 0; cj < 6; cj++) {
                float v0 = acc[si][cj][0], v1 = acc[si][cj][1], v2 = acc[si][cj][2], v3 = acc[si][cj][3];
                float mx = fmaxf(fmaxf(v0, v1), fmaxf(v2, v3));
                mx = fmaxf(mx, __shfl_xor(mx, 16));
                mx = fmaxf(mx, __shfl_xor(mx, 32));
                float e0 = __expf(v0 - mx), e1 = __expf(v1 - mx), e2 = __expf(v2 - mx), e3 = __expf(v3 - mx);
                float sm = e0 + e1 + e2 + e3;
                sm += __shfl_xor(sm, 16);
                sm += __shfl_xor(sm, 32);
                float rs = 1.0f / sm;
                u16x4 pk = { f2bf(e0 * rs), f2bf(e1 * rs), f2bf(e2 * rs), f2bf(e3 * rs) };
                int c = w * 96 + cj * 16 + l4 * 4;
                int chunk = ((c & 31) >> 3) ^ (s_l & 3);
                *(u16x4*)(smem + (c >> 5) * 4096 + s_l * 64 + chunk * 16 + (l4 & 1) * 8) = pk;
            }
        }
    }
    __syncthreads();

    // ===== phase 2: PV + bias + residual; P in LDS, U staged (uniform stream) =====
    const unsigned short* Ub = Ut2 + (size_t)b * 12 * DM_ * 32;
    auto stageU = [&](int kk2, int ec, int buf) {
        const unsigned short* slab = Ub + ((size_t)kk2 * DM_ + ec * 256) * 32;
        #pragma unroll
        for (int i = 0; i < 4; i++) {
            int idx = i * 256 + tid;
            int r = idx >> 2, m = (idx & 3) ^ ((r >> 1) & 3);
            gload16(slab + (size_t)r * 32 + m * 8, (char*)Ulds2 + buf * 16384 + idx * 16);
        }
    };

    for (int ec = 0; ec < 5; ec++) {
        f32x4 accp[4][4];
        #pragma unroll
        for (int si = 0; si < 4; si++)
            #pragma unroll
            for (int ej = 0; ej < 4; ej++) accp[si][ej] = zero;

        stageU(0, ec, 0);
        for (int kk2 = 0; kk2 < 12; kk2++) {
            if (kk2 < 11) {
                stageU(kk2 + 1, ec, (kk2 + 1) & 1);
                WAIT_VM(4);
            } else {
                WAIT_VM(0);
            }
            S_BARRIER();
            int buf = kk2 & 1;
            bf16x8 uf[4], pf[4];
            #pragma unroll
            for (int ej = 0; ej < 4; ej++)
                uf[ej] = *(const bf16x8*)&Ulds2[buf * 8192 + (w * 64 + ej * 16 + l15) * 32 + rdsw];
            #pragma unroll
            for (int si = 0; si < 4; si++) {
                int s_l = si * 16 + l15;
                pf[si] = *(const bf16x8*)(smem + kk2 * 4096 + s_l * 64 + ((l4 ^ (l15 & 3)) * 16));
            }
            __builtin_amdgcn_s_setprio(1);
            #pragma unroll
            for (int si = 0; si < 4; si++)
                #pragma unroll
                for (int ej = 0; ej < 4; ej++)
                    accp[si][ej] = __builtin_amdgcn_mfma_f32_16x16x32_bf16(uf[ej], pf[si], accp[si][ej], 0, 0, 0);
            __builtin_amdgcn_s_setprio(0);
            WAIT_LGKM0();
            S_BARRIER();
        }

        // epilogue for this ec (register loads/stores; counted stream is drained)
        #pragma unroll
        for (int ej = 0; ej < 4; ej++) {
            int e0c = ec * 256 + w * 64 + ej * 16 + l4 * 4;
            float4 b4 = *(const float4*)(bo + e0c);
            #pragma unroll
            for (int si = 0; si < 4; si++) {
                int srow = s0 + si * 16 + l15;
                size_t off = ((size_t)b * S_ + srow) * DM_ + e0c;
                float4 h4 = *(const float4*)(hid + off);
                f32x4 a = accp[si][ej];
                float4 o4;
                o4.x = a[0] + b4.x + h4.x;
                o4.y = a[1] + b4.y + h4.y;
                o4.z = a[2] + b4.z + h4.z;
                o4.w = a[3] + b4.w + h4.w;
                *(float4*)(out + off) = o4;
            }
        }
    }
}

extern "C" void kernel_launch(void* const* d_in, const int* in_sizes, int n_in,
                              void* d_out, int out_size, void* d_ws, size_t ws_size,
                              hipStream_t stream) {
    const float* hid  = (const float*)d_in[0];
    const float* enc  = (const float*)d_in[1];
    const float* wq   = (const float*)d_in[2];
    const float* wk   = (const float*)d_in[3];
    const float* wv   = (const float*)d_in[4];
    const float* wkd  = (const float*)d_in[5];
    const float* wvd  = (const float*)d_in[6];
    const float* wout = (const float*)d_in[7];
    const float* bo   = (const float*)d_in[8];
    float* out = (float*)d_out;

    char* ws = (char*)d_ws;
    unsigned short* At2    = (unsigned short*)(ws);               // 15,728,640
    unsigned short* Ut2    = (unsigned short*)(ws + 15728640);    // 15,728,640
    unsigned short* KV     = (unsigned short*)(ws + 31457280);    //  3,932,160
    unsigned short* wq_bf  = (unsigned short*)(ws + 35389440);    //  3,276,800
    unsigned short* woutT  = (unsigned short*)(ws + 38666240);    //  3,276,800
    unsigned short* wTk    = (unsigned short*)(ws + 41943040);    //  1,966,080
    unsigned short* wTv    = (unsigned short*)(ws + 43909120);    //  1,966,080
    unsigned short* wTkd   = (unsigned short*)(ws + 45875200);    //  1,966,080
    unsigned short* wTvd   = (unsigned short*)(ws + 47841280);    //  1,966,080 (end 49,807,360)

    k_prep<<<7040, 256, 0, stream>>>(wq, wk, wv, wkd, wvd, wout,
                                     wq_bf, wTk, wTv, wTkd, wTvd, woutT);
    k_projM<<<480, 256, 0, stream>>>(enc, wTk, wTv, wTkd, wTvd, KV);
    k_au<<<768, 256, 0, stream>>>(KV, wq_bf, woutT, At2, Ut2);
    k_fused<<<1024, 256, 0, stream>>>(hid, At2, Ut2, bo, out);
}